// Round 9
// baseline (280.789 us; speedup 1.0000x reference)
//
#include <hip/hip_runtime.h>
#include <math.h>

#define B_DIM 16
#define C_DIM 256
#define NV    40962
#define K_NEI 7
#define GRP   10241      // 4-n groups per b (last overlaps; duplicate writes bit-identical)
#define NBLK  641        // ceil(B_DIM*GRP/256) == ceil(NV/64) — same grid for all 3 phases

typedef float v2f __attribute__((ext_vector_type(2)));

// Device-wide barrier: all NBLK blocks are co-resident (launch_bounds(256,3)
// guarantees 3 blocks/CU -> 768 slots >= 641). Device-scope atomics + fences
// for cross-XCD coherence (per-XCD L2s are not coherent; plain volatile spin
// could read stale lines — atomic load goes to the coherent point).
__device__ __forceinline__ void grid_barrier(unsigned* cnt) {
    __syncthreads();
    if (threadIdx.x == 0) {
        __threadfence();                                   // release
        atomicAdd(cnt, 1u);                                // device-scope by default
        while (__hip_atomic_load(cnt, __ATOMIC_RELAXED,
                                 __HIP_MEMORY_SCOPE_AGENT) < NBLK) {
            __builtin_amdgcn_s_sleep(1);
        }
        __threadfence();                                   // acquire
    }
    __syncthreads();
}

__global__ __launch_bounds__(256, 3)
void fused_kernel(const float* __restrict__ x, const int* __restrict__ idx,
                  const float* __restrict__ W, const float* __restrict__ bias,
                  float* __restrict__ out,
                  float2* pool, float2* poolT, unsigned* bar) {
    // ---------- Phase 1: pool (R6-exact) ----------
    {
        int t = blockIdx.x * 256 + threadIdx.x;
        if (t < B_DIM * GRP) {
            int b = t / GRP;
            int r = t - b * GRP;
            int n0 = 4 * r; if (n0 > NV - 4) n0 = NV - 4;

            const float* xb = x + (size_t)b * C_DIM * NV + n0;
            float s0 = 0.f, s1 = 0.f, s2 = 0.f, s3 = 0.f;
            float m0 = -INFINITY, m1 = -INFINITY, m2 = -INFINITY, m3 = -INFINITY;
            #pragma unroll 16
            for (int c = 0; c < C_DIM; ++c) {
                const float* p = xb + (size_t)c * NV;
                v2f va = __builtin_nontemporal_load(reinterpret_cast<const v2f*>(p));
                v2f vb = __builtin_nontemporal_load(reinterpret_cast<const v2f*>(p + 2));
                s0 += va.x; s1 += va.y; s2 += vb.x; s3 += vb.y;
                m0 = fmaxf(m0, va.x); m1 = fmaxf(m1, va.y);
                m2 = fmaxf(m2, vb.x); m3 = fmaxf(m3, vb.y);
            }
            const float inv = 1.0f / (float)C_DIM;
            float4* pool4 = reinterpret_cast<float4*>(pool);
            size_t f4 = ((size_t)b * NV + n0) >> 1;
            pool4[f4]     = make_float4(s0 * inv, m0, s1 * inv, m1);
            pool4[f4 + 1] = make_float4(s2 * inv, m2, s3 * inv, m3);
        }
    }
    grid_barrier(bar + 0);

    // ---------- Phase 2: transpose [b][n] -> [n][b] (R2-exact) ----------
    {
        __shared__ float2 tile[64][17];
        int n0 = blockIdx.x * 64;
        int i  = threadIdx.x & 63;
        int bq = threadIdx.x >> 6;
        #pragma unroll
        for (int p = 0; p < 4; ++p) {
            int b = p * 4 + bq;
            if (n0 + i < NV)
                tile[i][b] = pool[(size_t)b * NV + n0 + i];
        }
        __syncthreads();
        int valid = NV - n0; if (valid > 64) valid = 64;
        int nf4 = valid * 8;
        float4* dst = reinterpret_cast<float4*>(poolT + (size_t)n0 * 16);
        for (int e = threadIdx.x; e < nf4; e += 256) {
            int e2 = e * 2;
            int n  = e2 >> 4;
            int b  = e2 & 15;
            float2 a0 = tile[n][b];
            float2 a1 = tile[n][b + 1];
            dst[e] = make_float4(a0.x, a0.y, a1.x, a1.y);
        }
    }
    grid_barrier(bar + 1);

    // ---------- Phase 3: att4 (R5-exact) ----------
    {
        int tid = threadIdx.x;
        int n   = blockIdx.x * 64 + (tid >> 2);
        int bq  = tid & 3;
        if (n < NV) {
            float w[2 * K_NEI];
            #pragma unroll
            for (int i = 0; i < 2 * K_NEI; ++i) w[i] = W[i];
            float bb = bias[0];

            float acc[4];
            #pragma unroll
            for (int r = 0; r < 4; ++r) acc[r] = bb;

            #pragma unroll
            for (int k = 0; k < K_NEI; ++k) {
                int j = idx[n * K_NEI + k];
                const float4* L = reinterpret_cast<const float4*>(poolT + (size_t)j * 16 + bq * 4);
                float4 v0 = L[0];
                float4 v1 = L[1];
                acc[0] = fmaf(w[2 * k + 1], v0.y, fmaf(w[2 * k], v0.x, acc[0]));
                acc[1] = fmaf(w[2 * k + 1], v0.w, fmaf(w[2 * k], v0.z, acc[1]));
                acc[2] = fmaf(w[2 * k + 1], v1.y, fmaf(w[2 * k], v1.x, acc[2]));
                acc[3] = fmaf(w[2 * k + 1], v1.w, fmaf(w[2 * k], v1.z, acc[3]));
            }
            #pragma unroll
            for (int r = 0; r < 4; ++r)
                out[(size_t)(bq * 4 + r) * NV + n] = 1.0f / (1.0f + expf(-acc[r]));
        }
    }
}

extern "C" void kernel_launch(void* const* d_in, const int* in_sizes, int n_in,
                              void* d_out, int out_size, void* d_ws, size_t ws_size,
                              hipStream_t stream) {
    const float* x     = (const float*)d_in[0];
    const int*   neigh = (const int*)  d_in[1];
    const float* W     = (const float*)d_in[2];
    const float* bias  = (const float*)d_in[3];
    float*       out   = (float*)d_out;

    const size_t POOL_BYTES = (size_t)B_DIM * NV * sizeof(float2); // 5.24 MB

    float2*   pool  = (float2*)d_ws;
    float2*   poolT = (float2*)((char*)d_ws + POOL_BYTES);
    unsigned* bar   = (unsigned*)((char*)d_ws + 2 * POOL_BYTES);

    // Reset barrier counters every launch (graph replays re-run this memset,
    // so the kernel is deterministic across replays).
    hipMemsetAsync(bar, 0, 2 * sizeof(unsigned), stream);

    fused_kernel<<<NBLK, 256, 0, stream>>>(x, neigh, W, bias, out, pool, poolT, bar);
}

// Round 10
// 167.240 us; speedup vs baseline: 1.6790x; 1.6790x over previous
//
#include <hip/hip_runtime.h>
#include <math.h>

#define B_DIM 16
#define C_DIM 256
#define NV    40962
#define K_NEI 7
#define GRP   10240        // 4-n groups per b; n 40960..40961 in tail block
#define NBLK_MAIN 640      // 16*GRP/256 exactly — no bounds check in main path

typedef float v2f __attribute__((ext_vector_type(2)));
typedef float v4f __attribute__((ext_vector_type(4)));

// Kernel 1: channel-wise mean+max with 16B/lane float4 loads on BOTH row
// parities. x rows: c even -> base%4==0 elements, c odd -> base%4==2.
// Even c: float4 at n0 (cols n0..n0+3). Odd c: float4 at n0-2 (16B-aligned!)
// holding cols n0-2..n0+1 -> shifted accumulators, reconciled at the end:
//   col n0,n0+1 <- own shifted regs; col n0+2,n0+3 <- thread tid+1 (LDS).
// tid==255 (block boundary) self-loads its missing 2 odd cols (masked float2
// inside the loop; one wave only). Sum = even-half + odd-half (reassociation
// error ~1e-6, threshold 1.3e-2).
__global__ __launch_bounds__(256) void pool_kernel(const float* __restrict__ x,
                                                   float4* __restrict__ pool) {
    if (blockIdx.x < NBLK_MAIN) {
        int t  = blockIdx.x * 256 + threadIdx.x;    // < 163,840 exactly
        int b  = t / GRP;
        int r  = t - b * GRP;
        int n0 = 4 * r;                             // 0..40956

        const float* xb = x + (size_t)b * C_DIM * NV + n0;
        bool last = (threadIdx.x == 255);

        float sE0 = 0.f, sE1 = 0.f, sE2 = 0.f, sE3 = 0.f;
        float mE0 = -INFINITY, mE1 = -INFINITY, mE2 = -INFINITY, mE3 = -INFINITY;
        float sO0 = 0.f, sO1 = 0.f, sO2 = 0.f, sO3 = 0.f;   // cols n0-2..n0+1
        float mO0 = -INFINITY, mO1 = -INFINITY, mO2 = -INFINITY, mO3 = -INFINITY;
        float sx2 = 0.f, sx3 = 0.f;                          // tid255 self: cols n0+2,n0+3
        float mx2 = -INFINITY, mx3 = -INFINITY;

        #pragma unroll 8
        for (int cp = 0; cp < C_DIM / 2; ++cp) {
            const float* pe = xb + (size_t)(2 * cp) * NV;          // 16B aligned
            const float* po = xb + (size_t)(2 * cp + 1) * NV - 2;  // 16B aligned
            v4f ve = __builtin_nontemporal_load(reinterpret_cast<const v4f*>(pe));
            v4f vo = __builtin_nontemporal_load(reinterpret_cast<const v4f*>(po));
            sE0 += ve.x; sE1 += ve.y; sE2 += ve.z; sE3 += ve.w;
            mE0 = fmaxf(mE0, ve.x); mE1 = fmaxf(mE1, ve.y);
            mE2 = fmaxf(mE2, ve.z); mE3 = fmaxf(mE3, ve.w);
            sO0 += vo.x; sO1 += vo.y; sO2 += vo.z; sO3 += vo.w;
            mO0 = fmaxf(mO0, vo.x); mO1 = fmaxf(mO1, vo.y);
            mO2 = fmaxf(mO2, vo.z); mO3 = fmaxf(mO3, vo.w);
            if (last) {                                            // wave 3 only
                v2f v = __builtin_nontemporal_load(
                            reinterpret_cast<const v2f*>(po + 4)); // cols n0+2,n0+3
                sx2 += v.x; sx3 += v.y;
                mx2 = fmaxf(mx2, v.x); mx3 = fmaxf(mx3, v.y);
            }
        }

        // Exchange: thread tid needs tid+1's (sO0,sO1,mO0,mO1) = cols n0+2,n0+3.
        __shared__ float4 shS[256];
        __shared__ float4 shM[256];
        shS[threadIdx.x] = make_float4(sO0, sO1, 0.f, 0.f);
        shM[threadIdx.x] = make_float4(mO0, mO1, 0.f, 0.f);
        __syncthreads();
        float ns2, ns3, nm2, nm3;
        if (!last) {
            float4 a = shS[threadIdx.x + 1];
            float4 c = shM[threadIdx.x + 1];
            ns2 = a.x; ns3 = a.y; nm2 = c.x; nm3 = c.y;
        } else {
            ns2 = sx2; ns3 = sx3; nm2 = mx2; nm3 = mx3;
        }

        const float inv = 1.0f / (float)C_DIM;
        float s0 = sE0 + sO2, s1 = sE1 + sO3, s2 = sE2 + ns2, s3 = sE3 + ns3;
        float m0 = fmaxf(mE0, mO2), m1 = fmaxf(mE1, mO3);
        float m2 = fmaxf(mE2, nm2), m3 = fmaxf(mE3, nm3);

        size_t f4 = ((size_t)b * NV + n0) >> 1;     // [b][n] float2 -> float4 index
        pool[f4]     = make_float4(s0 * inv, m0, s1 * inv, m1);
        pool[f4 + 1] = make_float4(s2 * inv, m2, s3 * inv, m3);
    } else {
        // Tail block (R8-proven): 32 columns (b 0..15, n in {40960,40961}) x 2 halves.
        __shared__ float2 part[64];
        int tid = threadIdx.x;
        if (tid < 64) {
            int col  = tid >> 1;
            int half = tid & 1;
            int b    = col >> 1;
            int n    = 40960 + (col & 1);
            const float* xb = x + (size_t)b * C_DIM * NV + n;
            float s = 0.f, m = -INFINITY;
            #pragma unroll 8
            for (int c = half * 128; c < half * 128 + 128; ++c) {
                float v = xb[(size_t)c * NV];
                s += v; m = fmaxf(m, v);
            }
            part[tid] = make_float2(s, m);
        }
        __syncthreads();
        if (tid < 64 && (tid & 1) == 0) {
            float2 a = part[tid], bb2 = part[tid + 1];
            int col = tid >> 1;
            int b   = col >> 1;
            int n   = 40960 + (col & 1);
            float2* poolf2 = reinterpret_cast<float2*>(pool);
            poolf2[(size_t)b * NV + n] =
                make_float2((a.x + bb2.x) * (1.0f / (float)C_DIM), fmaxf(a.y, bb2.y));
        }
    }
}

// Kernel 2 (proven): transpose pool [b][n] -> poolT [n][b].
__global__ void transpose_kernel(const float2* __restrict__ pool,
                                 float2* __restrict__ poolT) {
    __shared__ float2 tile[64][17];
    int n0 = blockIdx.x * 64;
    int i  = threadIdx.x & 63;
    int bq = threadIdx.x >> 6;        // 0..3
    #pragma unroll
    for (int p = 0; p < 4; ++p) {
        int b = p * 4 + bq;
        if (n0 + i < NV)
            tile[i][b] = pool[(size_t)b * NV + n0 + i];
    }
    __syncthreads();
    int valid = NV - n0; if (valid > 64) valid = 64;
    int nf4 = valid * 8;
    float4* dst = reinterpret_cast<float4*>(poolT + (size_t)n0 * 16);
    for (int e = threadIdx.x; e < nf4; e += 256) {
        int e2 = e * 2;
        int n  = e2 >> 4;
        int b  = e2 & 15;
        float2 a0 = tile[n][b];
        float2 a1 = tile[n][b + 1];
        dst[e] = make_float4(a0.x, a0.y, a1.x, a1.y);
    }
}

// Kernel 3 (proven): 4 threads per vertex, 4 b each; full-line gathers.
__global__ void att4_kernel(const float2* __restrict__ poolT,
                            const int* __restrict__ idx,
                            const float* __restrict__ W,
                            const float* __restrict__ bias,
                            float* __restrict__ out) {
    int tid = threadIdx.x;
    int n   = blockIdx.x * 64 + (tid >> 2);
    int bq  = tid & 3;
    if (n >= NV) return;

    float w[2 * K_NEI];
    #pragma unroll
    for (int i = 0; i < 2 * K_NEI; ++i) w[i] = W[i];
    float bb = bias[0];

    float acc[4];
    #pragma unroll
    for (int r = 0; r < 4; ++r) acc[r] = bb;

    #pragma unroll
    for (int k = 0; k < K_NEI; ++k) {
        int j = idx[n * K_NEI + k];
        const float4* L = reinterpret_cast<const float4*>(poolT + (size_t)j * 16 + bq * 4);
        float4 v0 = L[0];
        float4 v1 = L[1];
        acc[0] = fmaf(w[2 * k + 1], v0.y, fmaf(w[2 * k], v0.x, acc[0]));
        acc[1] = fmaf(w[2 * k + 1], v0.w, fmaf(w[2 * k], v0.z, acc[1]));
        acc[2] = fmaf(w[2 * k + 1], v1.y, fmaf(w[2 * k], v1.x, acc[2]));
        acc[3] = fmaf(w[2 * k + 1], v1.w, fmaf(w[2 * k], v1.z, acc[3]));
    }
    #pragma unroll
    for (int r = 0; r < 4; ++r)
        out[(size_t)(bq * 4 + r) * NV + n] = 1.0f / (1.0f + expf(-acc[r]));
}

extern "C" void kernel_launch(void* const* d_in, const int* in_sizes, int n_in,
                              void* d_out, int out_size, void* d_ws, size_t ws_size,
                              hipStream_t stream) {
    const float* x     = (const float*)d_in[0];
    const int*   neigh = (const int*)  d_in[1];
    const float* W     = (const float*)d_in[2];
    const float* bias  = (const float*)d_in[3];
    float*       out   = (float*)d_out;

    const size_t POOL_BYTES = (size_t)B_DIM * NV * sizeof(float2); // 5.24 MB

    float4* pool4 = (float4*)d_ws;                        // [b][n] staging
    float2* poolT = (float2*)((char*)d_ws + POOL_BYTES);  // [n][b]

    pool_kernel<<<NBLK_MAIN + 1, 256, 0, stream>>>(x, pool4);

    int ntile = (NV + 63) / 64;           // 641
    transpose_kernel<<<ntile, 256, 0, stream>>>((const float2*)d_ws, poolT);
    att4_kernel<<<ntile, 256, 0, stream>>>(poolT, neigh, W, bias, out);
}

// Round 11
// 128.529 us; speedup vs baseline: 2.1846x; 1.3012x over previous
//
#include <hip/hip_runtime.h>
#include <math.h>

#define B_DIM 16
#define C_DIM 256
#define NV    40962
#define K_NEI 7
#define NPAIR (NV / 2)   // 20481
#define GRP   10241      // groups of 4 consecutive n per b (last group overlaps)

typedef float v2f __attribute__((ext_vector_type(2)));

// Kernel 1 (R6-proven, 129.1 µs total): channel-wise mean+max.
// Thread = (b, group of 4 consecutive n), loaded as two float2 nt-loads
// (NV%4==2 -> float4 would be 8B-misaligned on odd c). Per c, a wave's two
// load instructions cover one contiguous 1KB span. Last group per b overlaps
// by 2 n; duplicate writes are bit-identical -> benign race, uniform loop.
__global__ __launch_bounds__(256) void pool_kernel(const float* __restrict__ x,
                                                   float4* __restrict__ pool) {
    int t = blockIdx.x * 256 + threadIdx.x;
    if (t >= B_DIM * GRP) return;
    int b = t / GRP;
    int r = t - b * GRP;
    int n0 = 4 * r; if (n0 > NV - 4) n0 = NV - 4;   // 40958 for r=10240

    const float* xb = x + (size_t)b * C_DIM * NV + n0;

    float s0 = 0.f, s1 = 0.f, s2 = 0.f, s3 = 0.f;
    float m0 = -INFINITY, m1 = -INFINITY, m2 = -INFINITY, m3 = -INFINITY;
    #pragma unroll 16
    for (int c = 0; c < C_DIM; ++c) {
        const float* p = xb + (size_t)c * NV;
        v2f va = __builtin_nontemporal_load(reinterpret_cast<const v2f*>(p));
        v2f vb = __builtin_nontemporal_load(reinterpret_cast<const v2f*>(p + 2));
        s0 += va.x; s1 += va.y; s2 += vb.x; s3 += vb.y;
        m0 = fmaxf(m0, va.x); m1 = fmaxf(m1, va.y);
        m2 = fmaxf(m2, vb.x); m3 = fmaxf(m3, vb.y);
    }
    const float inv = 1.0f / (float)C_DIM;
    size_t f4 = ((size_t)b * NV + n0) >> 1;          // [b][n] float2 -> float4 index
    pool[f4]     = make_float4(s0 * inv, m0, s1 * inv, m1);
    pool[f4 + 1] = make_float4(s2 * inv, m2, s3 * inv, m3);
}

// Kernel 2 (proven): transpose pool [b][n] -> poolT [n][b].
__global__ void transpose_kernel(const float2* __restrict__ pool,
                                 float2* __restrict__ poolT) {
    __shared__ float2 tile[64][17];
    int n0 = blockIdx.x * 64;
    int i  = threadIdx.x & 63;
    int bq = threadIdx.x >> 6;        // 0..3
    #pragma unroll
    for (int p = 0; p < 4; ++p) {
        int b = p * 4 + bq;
        if (n0 + i < NV)
            tile[i][b] = pool[(size_t)b * NV + n0 + i];
    }
    __syncthreads();
    int valid = NV - n0; if (valid > 64) valid = 64;
    int nf4 = valid * 8;
    float4* dst = reinterpret_cast<float4*>(poolT + (size_t)n0 * 16);
    for (int e = threadIdx.x; e < nf4; e += 256) {
        int e2 = e * 2;
        int n  = e2 >> 4;
        int b  = e2 & 15;
        float2 a0 = tile[n][b];
        float2 a1 = tile[n][b + 1];
        dst[e] = make_float4(a0.x, a0.y, a1.x, a1.y);
    }
}

// Kernel 3 (proven): 4 threads per vertex, 4 b each; full-line gathers.
__global__ void att4_kernel(const float2* __restrict__ poolT,
                            const int* __restrict__ idx,
                            const float* __restrict__ W,
                            const float* __restrict__ bias,
                            float* __restrict__ out) {
    int tid = threadIdx.x;
    int n   = blockIdx.x * 64 + (tid >> 2);
    int bq  = tid & 3;
    if (n >= NV) return;

    float w[2 * K_NEI];
    #pragma unroll
    for (int i = 0; i < 2 * K_NEI; ++i) w[i] = W[i];
    float bb = bias[0];

    float acc[4];
    #pragma unroll
    for (int r = 0; r < 4; ++r) acc[r] = bb;

    #pragma unroll
    for (int k = 0; k < K_NEI; ++k) {
        int j = idx[n * K_NEI + k];
        const float4* L = reinterpret_cast<const float4*>(poolT + (size_t)j * 16 + bq * 4);
        float4 v0 = L[0];
        float4 v1 = L[1];
        acc[0] = fmaf(w[2 * k + 1], v0.y, fmaf(w[2 * k], v0.x, acc[0]));
        acc[1] = fmaf(w[2 * k + 1], v0.w, fmaf(w[2 * k], v0.z, acc[1]));
        acc[2] = fmaf(w[2 * k + 1], v1.y, fmaf(w[2 * k], v1.x, acc[2]));
        acc[3] = fmaf(w[2 * k + 1], v1.w, fmaf(w[2 * k], v1.z, acc[3]));
    }
    #pragma unroll
    for (int r = 0; r < 4; ++r)
        out[(size_t)(bq * 4 + r) * NV + n] = 1.0f / (1.0f + expf(-acc[r]));
}

extern "C" void kernel_launch(void* const* d_in, const int* in_sizes, int n_in,
                              void* d_out, int out_size, void* d_ws, size_t ws_size,
                              hipStream_t stream) {
    const float* x     = (const float*)d_in[0];
    const int*   neigh = (const int*)  d_in[1];
    const float* W     = (const float*)d_in[2];
    const float* bias  = (const float*)d_in[3];
    float*       out   = (float*)d_out;

    const size_t POOL_BYTES = (size_t)B_DIM * NV * sizeof(float2); // 5.24 MB

    float4* pool4 = (float4*)d_ws;                        // [b][n] staging
    float2* poolT = (float2*)((char*)d_ws + POOL_BYTES);  // [n][b]

    int t1 = B_DIM * GRP;                 // 163,856
    pool_kernel<<<(t1 + 255) / 256, 256, 0, stream>>>(x, pool4);

    int ntile = (NV + 63) / 64;           // 641
    transpose_kernel<<<ntile, 256, 0, stream>>>((const float2*)d_ws, poolT);
    att4_kernel<<<ntile, 256, 0, stream>>>(poolT, neigh, W, bias, out);
}